// Round 10
// baseline (112.267 us; speedup 1.0000x reference)
//
#include <hip/hip_runtime.h>
#include <stdint.h>

// Problem dims
#define B_DIM 8192
#define I_DIM 512
#define O_DIM 512
#define KDIM  1536   // I_DIM * 3 features {silu, u0, u1}; u2 folded into bias
                     // via u2 = 1 - u0 - u1:  out += u0(Q0-Q2)+u1(Q1-Q2)+SUM_i Q2

// GEMM tile
#define BM 128
#define BN 64
#define BK 64        // two 32-wide halves; LDS layout [kh][rows][32]

using bf16x8 = __attribute__((ext_vector_type(8))) short;
using f32x4  = __attribute__((ext_vector_type(4))) float;

__device__ __forceinline__ unsigned short f2bf(float f) {
  union { float f; unsigned int u; } c; c.f = f;
  unsigned int x = c.u;
  unsigned int r = (x + 0x7fffu + ((x >> 16) & 1u)) >> 16;  // RNE
  return (unsigned short)r;
}

// silu + first-two basis-interp weights (u2 not needed: folded into bias)
__device__ __forceinline__ void feat3(float xf, unsigned short* o) {
  const float s = xf / (1.0f + __expf(-xf));          // silu, f32
  const float xc = fminf(fmaxf(xf, -1.0f), 1.0f);
  const float g = xc + 1.0f;                          // grid_idx in [0,2]
  int il = (int)floorf(g);
  if (il > 2) il = 2;
  const float fr = g - (float)il;
  int ih = il + (fr > 0.0f ? 1 : 0);
  if (ih > 2) ih = 2;
  const float u0 = (il == 0 ? 1.0f - fr : 0.0f) + (ih == 0 ? fr : 0.0f);
  const float u1 = (il == 1 ? 1.0f - fr : 0.0f) + (ih == 1 ? fr : 0.0f);
  o[0] = f2bf(s); o[1] = f2bf(u0); o[2] = f2bf(u1);
}

// ---------------------------------------------------------------------------
// Fused prologue.
// Blocks [0,2048): A[b][i*3+{0,1,2}] = {silu(x), u0, u1}  (thread = 8 i's,
//   24 bf16 = 3 uint4, fully coalesced).
// Blocks [2048,3072): per (i,o): q0,q1,q2 = (BASIS[g]·cp)*imp*sw (f32);
//   Wt[o][i*3+{0,1,2}] = {imp*bw, q0-q2, q1-q2} (bf16, N-major);
//   q2s[i*512+o] = q2 (f32 scratch for the bias reduction).
// BASIS: Gaussian pseudo-B-spline, knots linspace(-1.3,1.3,9), width .65,
// centers {-.8125,-.4875,-.1625,.1625,.4875}, rows normalized (+1e-6).
// ---------------------------------------------------------------------------
__global__ __launch_bounds__(256) void build_aw(const float* __restrict__ x,
                                                const float* __restrict__ cp,
                                                const float* __restrict__ bw,
                                                const float* __restrict__ sw,
                                                const float* __restrict__ imp,
                                                unsigned short* __restrict__ A,
                                                unsigned short* __restrict__ Wt,
                                                float* __restrict__ q2s) {
  if (blockIdx.x < 2048) {
    const int idx = blockIdx.x * 256 + threadIdx.x;   // b*64 + q
    const int b = idx >> 6;
    const int q = idx & 63;
    const float* xr = x + (size_t)b * I_DIM + q * 8;
    const float4 x0 = *reinterpret_cast<const float4*>(xr);
    const float4 x1 = *reinterpret_cast<const float4*>(xr + 4);
    union { unsigned short us[24]; uint4 v[3]; } out;
    const float xs[8] = {x0.x, x0.y, x0.z, x0.w, x1.x, x1.y, x1.z, x1.w};
#pragma unroll
    for (int j = 0; j < 8; ++j) feat3(xs[j], out.us + j * 3);
    uint4* dst = reinterpret_cast<uint4*>(A + (size_t)b * KDIM + q * 24);
    dst[0] = out.v[0]; dst[1] = out.v[1]; dst[2] = out.v[2];
  } else {
    const int idx = (blockIdx.x - 2048) * 256 + threadIdx.x;  // 512*512
    const int i = idx >> 9;
    const int o = idx & 511;
    const int e = i * O_DIM + o;
    const float im = imp[e];
    const float wb = im * bw[e];
    const float wsp = im * sw[e];
    const float* c = cp + (size_t)e * 5;
    const float c0 = c[0], c1 = c[1], c2 = c[2], c3 = c[3], c4 = c[4];
    const float q0 = (0.54336160f * c0 + 0.31713055f * c1 + 0.11226386f * c2 +
                      0.02410431f * c3 + 0.00313908f * c4) * wsp;
    const float q1 = (0.06493530f * c0 + 0.17651242f * c1 + 0.29101978f * c2 +
                      0.29101978f * c3 + 0.17651242f * c4) * wsp;
    const float q2 = (0.00313908f * c0 + 0.02410431f * c1 + 0.11226386f * c2 +
                      0.31713055f * c3 + 0.54336160f * c4) * wsp;
    q2s[e] = q2;
    unsigned short* wt = Wt + (size_t)o * KDIM + i * 3;
    wt[0] = f2bf(wb);
    wt[1] = f2bf(q0 - q2);
    wt[2] = f2bf(q1 - q2);
  }
}

// bias[o] = sum_i q2s[i*512+o]  (f32 exact; added in gemm epilogue)
__global__ __launch_bounds__(256) void bias_reduce(const float* __restrict__ q2s,
                                                   float* __restrict__ bias) {
  __shared__ float sm[256];
  const int o = blockIdx.x;
  const int t = threadIdx.x;
  sm[t] = q2s[(size_t)t * O_DIM + o] + q2s[(size_t)(t + 256) * O_DIM + o];
  __syncthreads();
#pragma unroll
  for (int off = 128; off > 0; off >>= 1) {
    if (t < off) sm[t] += sm[t + off];
    __syncthreads();
  }
  if (t == 0) bias[o] = sm[0];
}

// ---------------------------------------------------------------------------
// GEMM: C = A[M,K] * Wt[N,K]^T + bias[o], bf16 MFMA, BK=64, 4 waves (2x2),
// T1 XCD swizzle. Sync (T3/T4, R5-verified): 2-tile prefetch, counted
// s_waitcnt vmcnt(6), raw s_barrier; never vmcnt(0) in the main loop.
// R9 bank swizzle kept (data-identical involution): stage chunk c from global
// chunk c^((row>>1)&3), read kg = ((l>>4)^((l>>1)&3))*8.
// 24 K-tiles (KDIM=1536); tail derived by the same induction as R5's.
// ---------------------------------------------------------------------------
__device__ __forceinline__ void gload16(const void* g, void* lds) {
  __builtin_amdgcn_global_load_lds(
      (const __attribute__((address_space(1))) unsigned int*)g,
      (__attribute__((address_space(3))) unsigned int*)lds,
      16, 0, 0);
}

#define WAITV(n) asm volatile("s_waitcnt vmcnt(" #n ")" ::: "memory")

__global__ __launch_bounds__(256, 3) void gemm(const unsigned short* __restrict__ A,
                                               const unsigned short* __restrict__ Wt,
                                               const float* __restrict__ Bias,
                                               float* __restrict__ C) {
  // [buf][kh][rows][32] elems: A 2*2*128*32, B 2*2*64*32  -> 48 KB total
  __shared__ __align__(16) unsigned short As[2 * 8192];
  __shared__ __align__(16) unsigned short Bs[2 * 4096];

  // T1: XCD-aware swizzle (8 XCDs, 512 blocks, bijective since 512%8==0).
  const int bid = blockIdx.x;
  const int nb = (bid & 7) * 64 + (bid >> 3);
  const int mt = nb >> 3;
  const int nt = nb & 7;
  const int m0 = mt * BM;
  const int n0 = nt * BN;

  const int t = threadIdx.x;
  const int l = t & 63;
  const int w = t >> 6;
  const int wm = w >> 1;     // 2 m-halves of 64 rows
  const int wn = w & 1;      // 2 n-halves of 32 cols
  const int lr = l & 15;
  const int kg = ((l >> 4) ^ ((l >> 1) & 3)) * 8;

  f32x4 acc[4][2] = {};

  // Staging slot maps. LDS written linearly in slot order (rule #21); global
  // source chunk pre-swizzled: c_g = c ^ ((row>>1)&3).
  const unsigned short* gA[4];
  unsigned short* lA[2][4];
  const unsigned short* gB[2];
  unsigned short* lB[2][2];
#pragma unroll
  for (int i = 0; i < 4; ++i) {
    const int s = t + 256 * i;
    const int kh = s >> 9, row = (s >> 2) & 127, c = s & 3;
    gA[i] = A + (size_t)(m0 + row) * KDIM + kh * 32 + ((c ^ ((row >> 1) & 3)) * 8);
    lA[0][i] = As + s * 8;
    lA[1][i] = As + 8192 + s * 8;
  }
#pragma unroll
  for (int i = 0; i < 2; ++i) {
    const int s = t + 256 * i;
    const int kh = s >> 8, row = (s >> 2) & 63, c = s & 3;
    gB[i] = Wt + (size_t)(n0 + row) * KDIM + kh * 32 + ((c ^ ((row >> 1) & 3)) * 8);
    lB[0][i] = Bs + s * 8;
    lB[1][i] = Bs + 4096 + s * 8;
  }

  const int aoff = (wm * 64 + lr) * 32 + kg;   // + m*512 + kh*4096
  const int boff = (wn * 32 + lr) * 32 + kg;   // + n*512 + kh*2048

#define STAGE(buf, tile) do {                                                  \
    const int ko = (tile) * BK;                                                \
    _Pragma("unroll") for (int i = 0; i < 4; ++i) gload16(gA[i] + ko, lA[buf][i]); \
    _Pragma("unroll") for (int i = 0; i < 2; ++i) gload16(gB[i] + ko, lB[buf][i]); \
  } while (0)

#define COMPUTE(buf) do {                                                      \
    const unsigned short* Ab = As + (buf) * 8192;                              \
    const unsigned short* Bb = Bs + (buf) * 4096;                              \
    bf16x8 af[2][4], bfr[2][2];                                                \
    _Pragma("unroll") for (int h = 0; h < 2; ++h)                              \
      _Pragma("unroll") for (int m = 0; m < 4; ++m)                            \
        af[h][m] = *reinterpret_cast<const bf16x8*>(Ab + h * 4096 + aoff + m * 512); \
    _Pragma("unroll") for (int h = 0; h < 2; ++h)                              \
      _Pragma("unroll") for (int n = 0; n < 2; ++n)                            \
        bfr[h][n] = *reinterpret_cast<const bf16x8*>(Bb + h * 2048 + boff + n * 512); \
    _Pragma("unroll") for (int h = 0; h < 2; ++h)                              \
      _Pragma("unroll") for (int m = 0; m < 4; ++m)                            \
        _Pragma("unroll") for (int n = 0; n < 2; ++n)                          \
          acc[m][n] = __builtin_amdgcn_mfma_f32_16x16x32_bf16(af[h][m], bfr[h][n], acc[m][n], 0, 0, 0); \
  } while (0)

  // 24 K-tiles, 2 in flight. Static buf indices (rule #20).
  STAGE(0, 0);
  STAGE(1, 1);
#pragma unroll 1
  for (int tl = 0; tl < 20; tl += 2) {
    WAITV(6); __builtin_amdgcn_s_barrier();
    COMPUTE(0);
    __builtin_amdgcn_s_barrier();
    STAGE(0, tl + 2);
    WAITV(6); __builtin_amdgcn_s_barrier();
    COMPUTE(1);
    __builtin_amdgcn_s_barrier();
    STAGE(1, tl + 3);
  }
  // tiles 20..23 (stages 22,23 issued here; never vmcnt(0) until the end)
  WAITV(6); __builtin_amdgcn_s_barrier();
  COMPUTE(0);                       // tile 20
  __builtin_amdgcn_s_barrier();
  STAGE(0, 22);
  WAITV(6); __builtin_amdgcn_s_barrier();
  COMPUTE(1);                       // tile 21
  __builtin_amdgcn_s_barrier();
  STAGE(1, 23);
  WAITV(6); __builtin_amdgcn_s_barrier();
  COMPUTE(0);                       // tile 22
  WAITV(0); __builtin_amdgcn_s_barrier();
  COMPUTE(1);                       // tile 23

#undef STAGE
#undef COMPUTE

  // Epilogue: C/D layout col = lane&15, row = (lane>>4)*4 + reg [m89].
  // out[b,o] += bias[o] (exact f32 Q2 column-sum from the u2 fold).
  const int colb = n0 + wn * 32 + lr;
  const float b0 = Bias[colb];
  const float b1 = Bias[colb + 16];
#pragma unroll
  for (int m = 0; m < 4; ++m) {
#pragma unroll
    for (int n = 0; n < 2; ++n) {
      const int col = colb + n * 16;
      const float bb = n ? b1 : b0;
      const int rbase = m0 + wm * 64 + m * 16 + (l >> 4) * 4;
#pragma unroll
      for (int r = 0; r < 4; ++r)
        C[(size_t)(rbase + r) * O_DIM + col] = acc[m][n][r] + bb;
    }
  }
}

// ---------------------------------------------------------------------------
extern "C" void kernel_launch(void* const* d_in, const int* in_sizes, int n_in,
                              void* d_out, int out_size, void* d_ws, size_t ws_size,
                              hipStream_t stream) {
  const float* x   = (const float*)d_in[0];
  const float* cp  = (const float*)d_in[1];
  const float* bw  = (const float*)d_in[2];
  const float* sw  = (const float*)d_in[3];
  const float* imp = (const float*)d_in[4];
  float* out = (float*)d_out;

  unsigned short* Abuf = (unsigned short*)d_ws;                  // 25.2 MB bf16
  unsigned short* Wbuf = Abuf + (size_t)B_DIM * KDIM;            //  1.6 MB bf16
  float* q2s  = (float*)((char*)d_ws + 28u * 1024 * 1024);       //  1.0 MB f32
  float* bias = q2s + (size_t)I_DIM * O_DIM;                     //  2 KB  f32

  build_aw<<<2048 + 1024, 256, 0, stream>>>(x, cp, bw, sw, imp, Abuf, Wbuf, q2s);
  bias_reduce<<<O_DIM, 256, 0, stream>>>(q2s, bias);
  gemm<<<(B_DIM / BM) * (O_DIM / BN), 256, 0, stream>>>(Abuf, Wbuf, bias, out);
}